// Round 12
// baseline (53.901 us; speedup 1.0000x reference)
//
#include <hip/hip_runtime.h>
#include <hip/hip_bf16.h>
#include <math.h>

#define S_LEN 2048
#define N1 16
#define D 128
#define H 8
#define DI 128
#define K_SEL 512
#define SCALE_F 0.08838834764831845f  /* 1/sqrt(128) */
#define EPS_F 1e-9f

typedef __attribute__((ext_vector_type(8))) __bf16 bf16x8;
typedef __attribute__((ext_vector_type(4))) float f32x4;
typedef unsigned char uchar;
typedef unsigned long long ulong64;

// ---------- fp8 (OCP e4m3) pack helpers: hw conversion ----------
static __device__ __forceinline__ uint cvtpk_fp8(float a, float b) {
  uint r;
  asm volatile("v_cvt_pk_fp8_f32 %0, %1, %2" : "=v"(r) : "v"(a), "v"(b));
  return r & 0xffffu;  // instr writes low word only; mask undefined high bits
}
static __device__ __forceinline__ uint pack4_fp8(float4 v) {
  return cvtpk_fp8(v.x, v.y) | (cvtpk_fp8(v.z, v.w) << 16);
}

// bf16 helpers (fallback path)
static __device__ __forceinline__ ushort f2bf(float x) {
  uint u = __float_as_uint(x);
  uint r = u + 0x7fffu + ((u >> 16) & 1u);
  return (ushort)(r >> 16);
}
static __device__ __forceinline__ bf16x8 cvt8(float4 v0, float4 v1) {
  bf16x8 a;
  a[0] = (__bf16)v0.x; a[1] = (__bf16)v0.y; a[2] = (__bf16)v0.z; a[3] = (__bf16)v0.w;
  a[4] = (__bf16)v1.x; a[5] = (__bf16)v1.y; a[6] = (__bf16)v1.z; a[7] = (__bf16)v1.w;
  return a;
}

// ---- single fp8 pre-pass: blocks [0,256) pack comb rows, [256,768) pack A ----
__global__ __launch_bounds__(256)
void prep_all8(const float* __restrict__ key, const float* __restrict__ kidx,
               const float* __restrict__ query, const float* __restrict__ qidx,
               uchar* __restrict__ comb, uchar* __restrict__ ap,
               uchar* __restrict__ aip) {
  const int b = blockIdx.x;
  if (b < 256) {
    // comb row s = [128B key fp8][128B kidx fp8]
    const int gid = b * 256 + threadIdx.x;  // 0..65535 (= S*D/4)
    const int row = gid >> 5;
    const int i = gid & 31;
    *(uint*)(comb + (size_t)row * 256 + i * 4) = pack4_fp8(((const float4*)key)[gid]);
    *(uint*)(comb + (size_t)row * 256 + 128 + i * 4) =
        pack4_fp8(((const float4*)kidx)[gid]);
  } else {
    // A fragments pre-packed in per-lane MFMA layout:
    // ap[((t*4+ks)*64+lane)*8+j] = fp8(q[t][lane&15][ks*32+(lane>>4)*8+j])
    const int t = (b - 256) * 4 + (threadIdx.x >> 6);
    const int lane = threadIdx.x & 63;
    const int lg = lane >> 4;
    const int lr = lane & 15;
#pragma unroll
    for (int ks = 0; ks < 4; ++ks) {
      const int off = ks * 32 + lg * 8;
      const float* s = query + (size_t)t * (N1 * D) + lr * D + off;
      const float4 v0 = *(const float4*)s;
      const float4 v1 = *(const float4*)(s + 4);
      const ulong64 u = (ulong64)pack4_fp8(v0) | ((ulong64)pack4_fp8(v1) << 32);
      *(ulong64*)(ap + ((size_t)(t * 4 + ks) * 64 + lane) * 8) = u;
      ulong64 ui = 0;
      if (lr < H) {
        const float* s2 = qidx + (size_t)t * (H * DI) + lr * DI + off;
        const float4 w0 = *(const float4*)s2;
        const float4 w1 = *(const float4*)(s2 + 4);
        ui = (ulong64)pack4_fp8(w0) | ((ulong64)pack4_fp8(w1) << 32);
      }
      *(ulong64*)(aip + ((size_t)(t * 4 + ks) * 64 + lane) * 8) = ui;
    }
  }
}

// DMA one 16-row fp8 tile (4 KB) into LDS buffer TB: 4 instrs x 1KB.
// Instr j covers rows r = 4j + (lane>>4); within a row, 16 lanes cover its
// full 256B (4 lines) with chunk pre-swizzle c_src = c ^ (r&15) so the
// linear LDS dest ends up XOR-swizzled (verified R5/R9/R11).
#define STAGE8(TB, SVG)                                                        \
  do {                                                                         \
    _Pragma("unroll") for (int j_ = 0; j_ < 4; ++j_) {                         \
      const int r_ = 4 * j_ + (lane >> 4);                                     \
      const int srow_ = __shfl((SVG), r_);                                     \
      const uchar* src_ = comb + (size_t)srow_ * 256 +                         \
                          (((lane & 15) ^ (r_ & 15)) << 4);                    \
      __builtin_amdgcn_global_load_lds(                                        \
          (const __attribute__((address_space(1))) void*)(src_),               \
          (__attribute__((address_space(3))) void*)((TB) + j_ * 1024), 16, 0, 0);\
    }                                                                          \
  } while (0)

// ---- main (fp8): one block per row t; 4 waves x 128 cols; dbuf pipeline;
// 4 blocks/CU (32 KB LDS, VGPR cap 128) ----
__global__ __launch_bounds__(256, 4)
void sli_kl_mfma8(const float* __restrict__ weights,
                  const int* __restrict__ sidx,
                  const float* __restrict__ smax,
                  const float* __restrict__ ssum,
                  const uchar* __restrict__ comb,
                  const uchar* __restrict__ apack,
                  const uchar* __restrict__ aipack,
                  float* __restrict__ out) {
  const int t = blockIdx.x;
  const int tid = threadIdx.x;
  const int lane = tid & 63;
  const int w = tid >> 6;       // wave id 0..3
  const int lg = lane >> 4;     // lane group 0..3 -> k-slice
  const int lr = lane & 15;     // B-col / C-col within group

  __shared__ __align__(16) uchar tiles[4][2][4096];  // 2 x 4KB per wave
  __shared__ float red[5][4];
  uchar* tb0 = &tiles[w][0][0];
  uchar* tb1 = &tiles[w][1][0];

  // ---- per-lane column indices for this wave's 128 columns ----
  int sv[8];
#pragma unroll
  for (int g = 0; g < 8; ++g)
    sv[g] = sidx[t * K_SEL + w * 128 + g * 16 + lr];

  // ---- A fragments: pre-packed fp8, coalesced 8B/lane loads ----
  long aq[4], ai[4];
#pragma unroll
  for (int ks = 0; ks < 4; ++ks) {
    aq[ks] = *(const long*)(apack + ((size_t)(t * 4 + ks) * 64 + lane) * 8);
    ai[ks] = *(const long*)(aipack + ((size_t)(t * 4 + ks) * 64 + lane) * 8);
  }

  // ---- per-lane head constants (heads lg*4+j) ----
  float cnl[4], wgl[4];
#pragma unroll
  for (int j = 0; j < 4; ++j) {
    const int head = lg * 4 + j;
    cnl[j] = __expf(-smax[head * S_LEN + t]) / ssum[head * S_LEN + t];
    wgl[j] = (head < H) ? weights[t * H + head] : 0.f;
  }

  // ---- pin prologue VMEM before first STAGE (exact vmcnt counting) ----
  __builtin_amdgcn_sched_barrier(0);
  STAGE8(tb0, sv[0]);
  STAGE8(tb1, sv[1]);
  __builtin_amdgcn_sched_barrier(0);

  // ---- main loop: wait tile g (tile g+1's 4 loads in flight), read,
  // restage freed buffer with tile g+2 ----
  float pa[8], ia[8];
#pragma unroll
  for (int g = 0; g < 8; ++g) {
    uchar* tb = (g & 1) ? tb1 : tb0;
    if (g < 7) {
      asm volatile("s_waitcnt vmcnt(4)" ::: "memory");
    } else {
      asm volatile("s_waitcnt vmcnt(0)" ::: "memory");
    }
    __builtin_amdgcn_sched_barrier(0);
    long bA[4], bI[4];
#pragma unroll
    for (int ks = 0; ks < 4; ++ks) {
      const int cgA = 2 * ks + (lg >> 1);        // key chunk (16B units)
      const int cgI = 8 + 2 * ks + (lg >> 1);    // kidx chunk
      const int sub = (lg & 1) * 8;
      bA[ks] = *(const long*)(tb + lr * 256 + ((cgA ^ lr) << 4) + sub);
      bI[ks] = *(const long*)(tb + lr * 256 + ((cgI ^ lr) << 4) + sub);
    }
    __builtin_amdgcn_sched_barrier(0);
    asm volatile("s_waitcnt lgkmcnt(0)" ::: "memory");
    __builtin_amdgcn_sched_barrier(0);
    if (g < 6) STAGE8(tb, sv[g + 2]);
    f32x4 cA = {0.f, 0.f, 0.f, 0.f};
    f32x4 cI = {0.f, 0.f, 0.f, 0.f};
#pragma unroll
    for (int ks = 0; ks < 4; ++ks) {
      cA = __builtin_amdgcn_mfma_f32_16x16x32_fp8_fp8(aq[ks], bA[ks], cA, 0, 0, 0);
      cI = __builtin_amdgcn_mfma_f32_16x16x32_fp8_fp8(ai[ks], bI[ks], cI, 0, 0, 0);
    }
    float p = 0.f, e = 0.f;
#pragma unroll
    for (int j = 0; j < 4; ++j) {
      p = fmaf(__expf(cA[j] * SCALE_F), cnl[j], p);
      e = fmaf(wgl[j], fmaxf(cI[j], 0.f), e);
    }
    pa[g] = p;
    ia[g] = e;
  }

  // ---- cross-lane-group combine (sum over 16 heads) ----
#pragma unroll
  for (int g = 0; g < 8; ++g) {
    pa[g] += __shfl_xor(pa[g], 16); pa[g] += __shfl_xor(pa[g], 32);
    ia[g] += __shfl_xor(ia[g], 16); ia[g] += __shfl_xor(ia[g], 32);
  }

  // ---- pass 1: S_a, M ----
  float la = 0.f, le = -INFINITY;
#pragma unroll
  for (int g = 0; g < 8; ++g) {
    la += pa[g];
    le = fmaxf(le, ia[g]);
  }
#pragma unroll
  for (int off = 8; off >= 1; off >>= 1) {
    la += __shfl_xor(la, off);
    le = fmaxf(le, __shfl_xor(le, off));
  }
  if (lane == 0) { red[0][w] = la; red[1][w] = le; }
  __syncthreads();
  const float S_a = red[0][0] + red[0][1] + red[0][2] + red[0][3];
  const float M = fmaxf(fmaxf(red[1][0], red[1][1]), fmaxf(red[1][2], red[1][3]));
  const float inv_sa = 1.f / (S_a + EPS_F);

  // ---- pass 2: Z, T1, T2 ----
  float z = 0.f, t1 = 0.f, t2 = 0.f;
#pragma unroll
  for (int g = 0; g < 8; ++g) {
    const float e = ia[g];
    const float pn = pa[g] * inv_sa;
    z += __expf(e - M);
    t1 += pn * __logf(pn + EPS_F);
    t2 += pn * e;
  }
#pragma unroll
  for (int off = 8; off >= 1; off >>= 1) {
    z += __shfl_xor(z, off);
    t1 += __shfl_xor(t1, off);
    t2 += __shfl_xor(t2, off);
  }
  if (lane == 0) { red[2][w] = z; red[3][w] = t1; red[4][w] = t2; }
  __syncthreads();

  if (tid == 0) {
    const float Z = red[2][0] + red[2][1] + red[2][2] + red[2][3];
    const float T1 = red[3][0] + red[3][1] + red[3][2] + red[3][3];
    const float T2 = red[4][0] + red[4][1] + red[4][2] + red[4][3];
    const float total_pn = S_a * inv_sa;
    atomicAdd(out, (T1 - T2 + (M + __logf(Z)) * total_pn) * (1.0f / (float)S_LEN));
  }
}

// ======================= bf16 fallback path (small ws) =====================
__global__ __launch_bounds__(256)
void prep_comb(const float* __restrict__ key, const float* __restrict__ kidx,
               ushort* __restrict__ comb) {
  const int gid = blockIdx.x * 256 + threadIdx.x;
  const int row = gid >> 5;
  const int i = gid & 31;
  const float4 kv = ((const float4*)key)[gid];
  ushort4 o;
  o.x = f2bf(kv.x); o.y = f2bf(kv.y); o.z = f2bf(kv.z); o.w = f2bf(kv.w);
  *(ushort4*)(comb + (size_t)row * 256 + i * 4) = o;
  const float4 iv = ((const float4*)kidx)[gid];
  ushort4 p;
  p.x = f2bf(iv.x); p.y = f2bf(iv.y); p.z = f2bf(iv.z); p.w = f2bf(iv.w);
  *(ushort4*)(comb + (size_t)row * 256 + 128 + i * 4) = p;
}

__global__ __launch_bounds__(256)
void sli_kl_fused(const float* __restrict__ query,
                  const float* __restrict__ qidx,
                  const float* __restrict__ weights,
                  const int* __restrict__ sidx,
                  const float* __restrict__ smax,
                  const float* __restrict__ ssum,
                  const ushort* __restrict__ comb,
                  float* __restrict__ out) {
  const int t = blockIdx.x;
  const int tid = threadIdx.x;
  const int lane = tid & 63;
  const int w = tid >> 6;
  const int lg = lane >> 4;
  const int lr = lane & 15;
  __shared__ float red[5][4];

  int sv[8];
#pragma unroll
  for (int g = 0; g < 8; ++g)
    sv[g] = sidx[t * K_SEL + w * 128 + g * 16 + lr];

  bf16x8 aq[4], ai[4];
  {
    const float* qb = query + (size_t)t * (N1 * D) + lr * D;
#pragma unroll
    for (int ks = 0; ks < 4; ++ks) {
      const int off = ks * 32 + lg * 8;
      aq[ks] = cvt8(*(const float4*)(qb + off), *(const float4*)(qb + off + 4));
    }
    if (lr < H) {
      const float* ib = qidx + (size_t)t * (H * DI) + lr * DI;
#pragma unroll
      for (int ks = 0; ks < 4; ++ks) {
        const int off = ks * 32 + lg * 8;
        ai[ks] = cvt8(*(const float4*)(ib + off), *(const float4*)(ib + off + 4));
      }
    } else {
#pragma unroll
      for (int ks = 0; ks < 4; ++ks) {
        bf16x8 zz = {};
        ai[ks] = zz;
      }
    }
  }
  float cnl[4], wgl[4];
#pragma unroll
  for (int j = 0; j < 4; ++j) {
    const int head = lg * 4 + j;
    cnl[j] = __expf(-smax[head * S_LEN + t]) / ssum[head * S_LEN + t];
    wgl[j] = (head < H) ? weights[t * H + head] : 0.f;
  }
  float pa[8], ia[8];
#pragma unroll
  for (int g = 0; g < 8; ++g) {
    const ushort* rb = comb + (size_t)sv[g] * 256;
    f32x4 cA = {0.f, 0.f, 0.f, 0.f};
    f32x4 cI = {0.f, 0.f, 0.f, 0.f};
#pragma unroll
    for (int ks = 0; ks < 4; ++ks) {
      const bf16x8 vA = *(const bf16x8*)(rb + ks * 32 + lg * 8);
      const bf16x8 vI = *(const bf16x8*)(rb + 128 + ks * 32 + lg * 8);
      cA = __builtin_amdgcn_mfma_f32_16x16x32_bf16(aq[ks], vA, cA, 0, 0, 0);
      cI = __builtin_amdgcn_mfma_f32_16x16x32_bf16(ai[ks], vI, cI, 0, 0, 0);
    }
    float pp = 0.f, e = 0.f;
#pragma unroll
    for (int j = 0; j < 4; ++j) {
      pp = fmaf(__expf(cA[j] * SCALE_F), cnl[j], pp);
      e = fmaf(wgl[j], fmaxf(cI[j], 0.f), e);
    }
    pp += __shfl_xor(pp, 16); pp += __shfl_xor(pp, 32);
    e += __shfl_xor(e, 16); e += __shfl_xor(e, 32);
    pa[g] = pp;
    ia[g] = e;
  }
  float la = 0.f, le = -INFINITY;
#pragma unroll
  for (int g = 0; g < 8; ++g) { la += pa[g]; le = fmaxf(le, ia[g]); }
#pragma unroll
  for (int off = 8; off >= 1; off >>= 1) {
    la += __shfl_xor(la, off);
    le = fmaxf(le, __shfl_xor(le, off));
  }
  if (lane == 0) { red[0][w] = la; red[1][w] = le; }
  __syncthreads();
  const float S_a = red[0][0] + red[0][1] + red[0][2] + red[0][3];
  const float M = fmaxf(fmaxf(red[1][0], red[1][1]), fmaxf(red[1][2], red[1][3]));
  const float inv_sa = 1.f / (S_a + EPS_F);
  float z = 0.f, t1 = 0.f, t2 = 0.f;
#pragma unroll
  for (int g = 0; g < 8; ++g) {
    const float e = ia[g];
    const float pn = pa[g] * inv_sa;
    z += __expf(e - M);
    t1 += pn * __logf(pn + EPS_F);
    t2 += pn * e;
  }
#pragma unroll
  for (int off = 8; off >= 1; off >>= 1) {
    z += __shfl_xor(z, off);
    t1 += __shfl_xor(t1, off);
    t2 += __shfl_xor(t2, off);
  }
  if (lane == 0) { red[2][w] = z; red[3][w] = t1; red[4][w] = t2; }
  __syncthreads();
  if (tid == 0) {
    const float Z = red[2][0] + red[2][1] + red[2][2] + red[2][3];
    const float T1 = red[3][0] + red[3][1] + red[3][2] + red[3][3];
    const float T2 = red[4][0] + red[4][1] + red[4][2] + red[4][3];
    const float total_pn = S_a * inv_sa;
    atomicAdd(out, (T1 - T2 + (M + __logf(Z)) * total_pn) * (1.0f / (float)S_LEN));
  }
}

extern "C" void kernel_launch(void* const* d_in, const int* in_sizes, int n_in,
                              void* d_out, int out_size, void* d_ws, size_t ws_size,
                              hipStream_t stream) {
  const float* query = (const float*)d_in[0];
  const float* key = (const float*)d_in[1];
  const float* qidx = (const float*)d_in[2];
  const float* kidx = (const float*)d_in[3];
  const float* weights = (const float*)d_in[4];
  const int* sidx = (const int*)d_in[5];
  const float* smax = (const float*)d_in[6];
  const float* ssum = (const float*)d_in[7];
  float* out = (float*)d_out;

  const size_t apack_b = (size_t)S_LEN * 4 * 64 * 8;       // 4 MiB each
  const size_t comb8_b = (size_t)S_LEN * 256;              // 512 KiB
  const size_t need = 2 * apack_b + comb8_b;

  hipMemsetAsync(out, 0, sizeof(float), stream);

  if (ws_size >= need) {
    uchar* apack = (uchar*)d_ws;
    uchar* aipack = apack + apack_b;
    uchar* comb8 = aipack + apack_b;

    prep_all8<<<dim3(256 + S_LEN / 4), dim3(256), 0, stream>>>(
        key, kidx, query, qidx, comb8, apack, aipack);
    sli_kl_mfma8<<<dim3(S_LEN), dim3(256), 0, stream>>>(
        weights, sidx, smax, ssum, comb8, apack, aipack, out);
  } else {
    ushort* comb = (ushort*)d_ws;  // 1 MiB
    prep_comb<<<dim3((S_LEN * D / 4) / 256), dim3(256), 0, stream>>>(key, kidx, comb);
    sli_kl_fused<<<dim3(S_LEN), dim3(256), 0, stream>>>(
        query, qidx, weights, sidx, smax, ssum, comb, out);
  }
}

// Round 13
// 37.735 us; speedup vs baseline: 1.4284x; 1.4284x over previous
//
#include <hip/hip_runtime.h>
#include <hip/hip_bf16.h>
#include <math.h>

#define S_LEN 2048
#define N1 16
#define D 128
#define H 8
#define DI 128
#define K_SEL 512
#define SCALE_F 0.08838834764831845f  /* 1/sqrt(128) */
#define EPS_F 1e-9f

typedef __attribute__((ext_vector_type(8))) __bf16 bf16x8;
typedef __attribute__((ext_vector_type(4))) float f32x4;
typedef unsigned char uchar;
typedef unsigned long long ulong64;

// ---------- fp8 (OCP e4m3) pack helpers: hw conversion ----------
static __device__ __forceinline__ uint cvtpk_fp8(float a, float b) {
  uint r;
  asm volatile("v_cvt_pk_fp8_f32 %0, %1, %2" : "=v"(r) : "v"(a), "v"(b));
  return r & 0xffffu;  // instr writes low word only; mask undefined high bits
}
static __device__ __forceinline__ uint pack4_fp8(float4 v) {
  return cvtpk_fp8(v.x, v.y) | (cvtpk_fp8(v.z, v.w) << 16);
}

// bf16 helpers (fallback path)
static __device__ __forceinline__ ushort f2bf(float x) {
  uint u = __float_as_uint(x);
  uint r = u + 0x7fffu + ((u >> 16) & 1u);
  return (ushort)(r >> 16);
}
static __device__ __forceinline__ bf16x8 cvt8(float4 v0, float4 v1) {
  bf16x8 a;
  a[0] = (__bf16)v0.x; a[1] = (__bf16)v0.y; a[2] = (__bf16)v0.z; a[3] = (__bf16)v0.w;
  a[4] = (__bf16)v1.x; a[5] = (__bf16)v1.y; a[6] = (__bf16)v1.z; a[7] = (__bf16)v1.w;
  return a;
}

// ---- single fp8 pre-pass: blocks [0,256) pack comb rows, [256,768) pack A ----
__global__ __launch_bounds__(256)
void prep_all8(const float* __restrict__ key, const float* __restrict__ kidx,
               const float* __restrict__ query, const float* __restrict__ qidx,
               uchar* __restrict__ comb, uchar* __restrict__ ap,
               uchar* __restrict__ aip) {
  const int b = blockIdx.x;
  if (b < 256) {
    // comb row s = [128B key fp8][128B kidx fp8]
    const int gid = b * 256 + threadIdx.x;  // 0..65535 (= S*D/4)
    const int row = gid >> 5;
    const int i = gid & 31;
    *(uint*)(comb + (size_t)row * 256 + i * 4) = pack4_fp8(((const float4*)key)[gid]);
    *(uint*)(comb + (size_t)row * 256 + 128 + i * 4) =
        pack4_fp8(((const float4*)kidx)[gid]);
  } else {
    // A fragments pre-packed in per-lane MFMA layout:
    // ap[((t*4+ks)*64+lane)*8+j] = fp8(q[t][lane&15][ks*32+(lane>>4)*8+j])
    const int t = (b - 256) * 4 + (threadIdx.x >> 6);
    const int lane = threadIdx.x & 63;
    const int lg = lane >> 4;
    const int lr = lane & 15;
#pragma unroll
    for (int ks = 0; ks < 4; ++ks) {
      const int off = ks * 32 + lg * 8;
      const float* s = query + (size_t)t * (N1 * D) + lr * D + off;
      const float4 v0 = *(const float4*)s;
      const float4 v1 = *(const float4*)(s + 4);
      const ulong64 u = (ulong64)pack4_fp8(v0) | ((ulong64)pack4_fp8(v1) << 32);
      *(ulong64*)(ap + ((size_t)(t * 4 + ks) * 64 + lane) * 8) = u;
      ulong64 ui = 0;
      if (lr < H) {
        const float* s2 = qidx + (size_t)t * (H * DI) + lr * DI + off;
        const float4 w0 = *(const float4*)s2;
        const float4 w1 = *(const float4*)(s2 + 4);
        ui = (ulong64)pack4_fp8(w0) | ((ulong64)pack4_fp8(w1) << 32);
      }
      *(ulong64*)(aip + ((size_t)(t * 4 + ks) * 64 + lane) * 8) = ui;
    }
  }
}

// DMA one 16-row fp8 tile (4 KB) into LDS buffer TB: 4 instrs x 1KB.
// Instr j covers rows r = 4j + (lane>>4); within a row, 16 lanes cover its
// full 256B (4 lines) with chunk pre-swizzle c_src = c ^ (r&15) so the
// linear LDS dest ends up XOR-swizzled (verified R5/R9/R11).
#define STAGE8(TB, SVG)                                                        \
  do {                                                                         \
    _Pragma("unroll") for (int j_ = 0; j_ < 4; ++j_) {                         \
      const int r_ = 4 * j_ + (lane >> 4);                                     \
      const int srow_ = __shfl((SVG), r_);                                     \
      const uchar* src_ = comb + (size_t)srow_ * 256 +                         \
                          (((lane & 15) ^ (r_ & 15)) << 4);                    \
      __builtin_amdgcn_global_load_lds(                                        \
          (const __attribute__((address_space(1))) void*)(src_),               \
          (__attribute__((address_space(3))) void*)((TB) + j_ * 1024), 16, 0, 0);\
    }                                                                          \
  } while (0)

// ---- main (fp8): one block per row t; 4 waves x 128 cols; dbuf pipeline;
// R11's exact proven config: __launch_bounds__(256, 2), pkl store ----
__global__ __launch_bounds__(256, 2)
void sli_kl_mfma8(const float* __restrict__ weights,
                  const int* __restrict__ sidx,
                  const float* __restrict__ smax,
                  const float* __restrict__ ssum,
                  const uchar* __restrict__ comb,
                  const uchar* __restrict__ apack,
                  const uchar* __restrict__ aipack,
                  float* __restrict__ pkl,
                  float* __restrict__ out) {
  const int t = blockIdx.x;
  const int tid = threadIdx.x;
  const int lane = tid & 63;
  const int w = tid >> 6;       // wave id 0..3
  const int lg = lane >> 4;     // lane group 0..3 -> k-slice
  const int lr = lane & 15;     // B-col / C-col within group

  __shared__ __align__(16) uchar tiles[4][2][4096];  // 2 x 4KB per wave
  __shared__ float red[5][4];
  uchar* tb0 = &tiles[w][0][0];
  uchar* tb1 = &tiles[w][1][0];

  // ---- per-lane column indices for this wave's 128 columns ----
  int sv[8];
#pragma unroll
  for (int g = 0; g < 8; ++g)
    sv[g] = sidx[t * K_SEL + w * 128 + g * 16 + lr];

  // ---- A fragments: pre-packed fp8, coalesced 8B/lane loads ----
  long aq[4], ai[4];
#pragma unroll
  for (int ks = 0; ks < 4; ++ks) {
    aq[ks] = *(const long*)(apack + ((size_t)(t * 4 + ks) * 64 + lane) * 8);
    ai[ks] = *(const long*)(aipack + ((size_t)(t * 4 + ks) * 64 + lane) * 8);
  }

  // ---- per-lane head constants (heads lg*4+j) ----
  float cnl[4], wgl[4];
#pragma unroll
  for (int j = 0; j < 4; ++j) {
    const int head = lg * 4 + j;
    cnl[j] = __expf(-smax[head * S_LEN + t]) / ssum[head * S_LEN + t];
    wgl[j] = (head < H) ? weights[t * H + head] : 0.f;
  }

  // ---- pin prologue VMEM before first STAGE (exact vmcnt counting) ----
  __builtin_amdgcn_sched_barrier(0);
  STAGE8(tb0, sv[0]);
  STAGE8(tb1, sv[1]);
  __builtin_amdgcn_sched_barrier(0);

  // ---- main loop: wait tile g (tile g+1's 4 loads in flight), read,
  // restage freed buffer with tile g+2 ----
  float pa[8], ia[8];
#pragma unroll
  for (int g = 0; g < 8; ++g) {
    uchar* tb = (g & 1) ? tb1 : tb0;
    if (g < 7) {
      asm volatile("s_waitcnt vmcnt(4)" ::: "memory");
    } else {
      asm volatile("s_waitcnt vmcnt(0)" ::: "memory");
    }
    __builtin_amdgcn_sched_barrier(0);
    long bA[4], bI[4];
#pragma unroll
    for (int ks = 0; ks < 4; ++ks) {
      const int cgA = 2 * ks + (lg >> 1);        // key chunk (16B units)
      const int cgI = 8 + 2 * ks + (lg >> 1);    // kidx chunk
      const int sub = (lg & 1) * 8;
      bA[ks] = *(const long*)(tb + lr * 256 + ((cgA ^ lr) << 4) + sub);
      bI[ks] = *(const long*)(tb + lr * 256 + ((cgI ^ lr) << 4) + sub);
    }
    __builtin_amdgcn_sched_barrier(0);
    asm volatile("s_waitcnt lgkmcnt(0)" ::: "memory");
    __builtin_amdgcn_sched_barrier(0);
    if (g < 6) STAGE8(tb, sv[g + 2]);
    f32x4 cA = {0.f, 0.f, 0.f, 0.f};
    f32x4 cI = {0.f, 0.f, 0.f, 0.f};
#pragma unroll
    for (int ks = 0; ks < 4; ++ks) {
      cA = __builtin_amdgcn_mfma_f32_16x16x32_fp8_fp8(aq[ks], bA[ks], cA, 0, 0, 0);
      cI = __builtin_amdgcn_mfma_f32_16x16x32_fp8_fp8(ai[ks], bI[ks], cI, 0, 0, 0);
    }
    float p = 0.f, e = 0.f;
#pragma unroll
    for (int j = 0; j < 4; ++j) {
      p = fmaf(__expf(cA[j] * SCALE_F), cnl[j], p);
      e = fmaf(wgl[j], fmaxf(cI[j], 0.f), e);
    }
    pa[g] = p;
    ia[g] = e;
  }

  // ---- cross-lane-group combine (sum over 16 heads) ----
#pragma unroll
  for (int g = 0; g < 8; ++g) {
    pa[g] += __shfl_xor(pa[g], 16); pa[g] += __shfl_xor(pa[g], 32);
    ia[g] += __shfl_xor(ia[g], 16); ia[g] += __shfl_xor(ia[g], 32);
  }

  // ---- pass 1: S_a, M ----
  float la = 0.f, le = -INFINITY;
#pragma unroll
  for (int g = 0; g < 8; ++g) {
    la += pa[g];
    le = fmaxf(le, ia[g]);
  }
#pragma unroll
  for (int off = 8; off >= 1; off >>= 1) {
    la += __shfl_xor(la, off);
    le = fmaxf(le, __shfl_xor(le, off));
  }
  if (lane == 0) { red[0][w] = la; red[1][w] = le; }
  __syncthreads();
  const float S_a = red[0][0] + red[0][1] + red[0][2] + red[0][3];
  const float M = fmaxf(fmaxf(red[1][0], red[1][1]), fmaxf(red[1][2], red[1][3]));
  const float inv_sa = 1.f / (S_a + EPS_F);

  // ---- pass 2: Z, T1, T2 ----
  float z = 0.f, t1 = 0.f, t2 = 0.f;
#pragma unroll
  for (int g = 0; g < 8; ++g) {
    const float e = ia[g];
    const float pn = pa[g] * inv_sa;
    z += __expf(e - M);
    t1 += pn * __logf(pn + EPS_F);
    t2 += pn * e;
  }
#pragma unroll
  for (int off = 8; off >= 1; off >>= 1) {
    z += __shfl_xor(z, off);
    t1 += __shfl_xor(t1, off);
    t2 += __shfl_xor(t2, off);
  }
  if (lane == 0) { red[2][w] = z; red[3][w] = t1; red[4][w] = t2; }
  __syncthreads();

  if (tid == 0) {
    const float Z = red[2][0] + red[2][1] + red[2][2] + red[2][3];
    const float T1 = red[3][0] + red[3][1] + red[3][2] + red[3][3];
    const float T2 = red[4][0] + red[4][1] + red[4][2] + red[4][3];
    const float total_pn = S_a * inv_sa;
    const float kl_row = (T1 - T2 + (M + __logf(Z)) * total_pn) * (1.0f / (float)S_LEN);
    if (pkl) pkl[t] = kl_row;
    else atomicAdd(out, kl_row);
  }
}

// ---- final reduce: 2048 partials -> scalar ----
__global__ __launch_bounds__(256)
void reduce_kl(const float* __restrict__ pkl, float* __restrict__ out) {
  const int tid = threadIdx.x;
  float s = 0.f;
  for (int i = tid; i < S_LEN; i += 256) s += pkl[i];
#pragma unroll
  for (int off = 32; off >= 1; off >>= 1) s += __shfl_xor(s, off);
  __shared__ float r[4];
  if ((tid & 63) == 0) r[tid >> 6] = s;
  __syncthreads();
  if (tid == 0) out[0] = r[0] + r[1] + r[2] + r[3];
}

// ======================= bf16 fallback path (small ws) =====================
__global__ __launch_bounds__(256)
void prep_comb(const float* __restrict__ key, const float* __restrict__ kidx,
               ushort* __restrict__ comb) {
  const int gid = blockIdx.x * 256 + threadIdx.x;
  const int row = gid >> 5;
  const int i = gid & 31;
  const float4 kv = ((const float4*)key)[gid];
  ushort4 o;
  o.x = f2bf(kv.x); o.y = f2bf(kv.y); o.z = f2bf(kv.z); o.w = f2bf(kv.w);
  *(ushort4*)(comb + (size_t)row * 256 + i * 4) = o;
  const float4 iv = ((const float4*)kidx)[gid];
  ushort4 p;
  p.x = f2bf(iv.x); p.y = f2bf(iv.y); p.z = f2bf(iv.z); p.w = f2bf(iv.w);
  *(ushort4*)(comb + (size_t)row * 256 + 128 + i * 4) = p;
}

__global__ __launch_bounds__(256)
void sli_kl_fused(const float* __restrict__ query,
                  const float* __restrict__ qidx,
                  const float* __restrict__ weights,
                  const int* __restrict__ sidx,
                  const float* __restrict__ smax,
                  const float* __restrict__ ssum,
                  const ushort* __restrict__ comb,
                  float* __restrict__ out) {
  const int t = blockIdx.x;
  const int tid = threadIdx.x;
  const int lane = tid & 63;
  const int w = tid >> 6;
  const int lg = lane >> 4;
  const int lr = lane & 15;
  __shared__ float red[5][4];

  int sv[8];
#pragma unroll
  for (int g = 0; g < 8; ++g)
    sv[g] = sidx[t * K_SEL + w * 128 + g * 16 + lr];

  bf16x8 aq[4], ai[4];
  {
    const float* qb = query + (size_t)t * (N1 * D) + lr * D;
#pragma unroll
    for (int ks = 0; ks < 4; ++ks) {
      const int off = ks * 32 + lg * 8;
      aq[ks] = cvt8(*(const float4*)(qb + off), *(const float4*)(qb + off + 4));
    }
    if (lr < H) {
      const float* ib = qidx + (size_t)t * (H * DI) + lr * DI;
#pragma unroll
      for (int ks = 0; ks < 4; ++ks) {
        const int off = ks * 32 + lg * 8;
        ai[ks] = cvt8(*(const float4*)(ib + off), *(const float4*)(ib + off + 4));
      }
    } else {
#pragma unroll
      for (int ks = 0; ks < 4; ++ks) {
        bf16x8 zz = {};
        ai[ks] = zz;
      }
    }
  }
  float cnl[4], wgl[4];
#pragma unroll
  for (int j = 0; j < 4; ++j) {
    const int head = lg * 4 + j;
    cnl[j] = __expf(-smax[head * S_LEN + t]) / ssum[head * S_LEN + t];
    wgl[j] = (head < H) ? weights[t * H + head] : 0.f;
  }
  float pa[8], ia[8];
#pragma unroll
  for (int g = 0; g < 8; ++g) {
    const ushort* rb = comb + (size_t)sv[g] * 256;
    f32x4 cA = {0.f, 0.f, 0.f, 0.f};
    f32x4 cI = {0.f, 0.f, 0.f, 0.f};
#pragma unroll
    for (int ks = 0; ks < 4; ++ks) {
      const bf16x8 vA = *(const bf16x8*)(rb + ks * 32 + lg * 8);
      const bf16x8 vI = *(const bf16x8*)(rb + 128 + ks * 32 + lg * 8);
      cA = __builtin_amdgcn_mfma_f32_16x16x32_bf16(aq[ks], vA, cA, 0, 0, 0);
      cI = __builtin_amdgcn_mfma_f32_16x16x32_bf16(ai[ks], vI, cI, 0, 0, 0);
    }
    float pp = 0.f, e = 0.f;
#pragma unroll
    for (int j = 0; j < 4; ++j) {
      pp = fmaf(__expf(cA[j] * SCALE_F), cnl[j], pp);
      e = fmaf(wgl[j], fmaxf(cI[j], 0.f), e);
    }
    pp += __shfl_xor(pp, 16); pp += __shfl_xor(pp, 32);
    e += __shfl_xor(e, 16); e += __shfl_xor(e, 32);
    pa[g] = pp;
    ia[g] = e;
  }
  float la = 0.f, le = -INFINITY;
#pragma unroll
  for (int g = 0; g < 8; ++g) { la += pa[g]; le = fmaxf(le, ia[g]); }
#pragma unroll
  for (int off = 8; off >= 1; off >>= 1) {
    la += __shfl_xor(la, off);
    le = fmaxf(le, __shfl_xor(le, off));
  }
  if (lane == 0) { red[0][w] = la; red[1][w] = le; }
  __syncthreads();
  const float S_a = red[0][0] + red[0][1] + red[0][2] + red[0][3];
  const float M = fmaxf(fmaxf(red[1][0], red[1][1]), fmaxf(red[1][2], red[1][3]));
  const float inv_sa = 1.f / (S_a + EPS_F);
  float z = 0.f, t1 = 0.f, t2 = 0.f;
#pragma unroll
  for (int g = 0; g < 8; ++g) {
    const float e = ia[g];
    const float pn = pa[g] * inv_sa;
    z += __expf(e - M);
    t1 += pn * __logf(pn + EPS_F);
    t2 += pn * e;
  }
#pragma unroll
  for (int off = 8; off >= 1; off >>= 1) {
    z += __shfl_xor(z, off);
    t1 += __shfl_xor(t1, off);
    t2 += __shfl_xor(t2, off);
  }
  if (lane == 0) { red[2][w] = z; red[3][w] = t1; red[4][w] = t2; }
  __syncthreads();
  if (tid == 0) {
    const float Z = red[2][0] + red[2][1] + red[2][2] + red[2][3];
    const float T1 = red[3][0] + red[3][1] + red[3][2] + red[3][3];
    const float T2 = red[4][0] + red[4][1] + red[4][2] + red[4][3];
    const float total_pn = S_a * inv_sa;
    atomicAdd(out, (T1 - T2 + (M + __logf(Z)) * total_pn) * (1.0f / (float)S_LEN));
  }
}

extern "C" void kernel_launch(void* const* d_in, const int* in_sizes, int n_in,
                              void* d_out, int out_size, void* d_ws, size_t ws_size,
                              hipStream_t stream) {
  const float* query = (const float*)d_in[0];
  const float* key = (const float*)d_in[1];
  const float* qidx = (const float*)d_in[2];
  const float* kidx = (const float*)d_in[3];
  const float* weights = (const float*)d_in[4];
  const int* sidx = (const int*)d_in[5];
  const float* smax = (const float*)d_in[6];
  const float* ssum = (const float*)d_in[7];
  float* out = (float*)d_out;

  const size_t apack_b = (size_t)S_LEN * 4 * 64 * 8;       // 4 MiB each
  const size_t comb8_b = (size_t)S_LEN * 256;              // 512 KiB
  const size_t pkl_b = (size_t)S_LEN * sizeof(float);      // 8 KiB
  const size_t need = 2 * apack_b + comb8_b + pkl_b;

  if (ws_size >= need) {
    uchar* apack = (uchar*)d_ws;
    uchar* aipack = apack + apack_b;
    uchar* comb8 = aipack + apack_b;
    float* pkl = (float*)(comb8 + comb8_b);

    prep_all8<<<dim3(256 + S_LEN / 4), dim3(256), 0, stream>>>(
        key, kidx, query, qidx, comb8, apack, aipack);
    sli_kl_mfma8<<<dim3(S_LEN), dim3(256), 0, stream>>>(
        weights, sidx, smax, ssum, comb8, apack, aipack, pkl, out);
    reduce_kl<<<dim3(1), dim3(256), 0, stream>>>(pkl, out);
  } else {
    ushort* comb = (ushort*)d_ws;  // 1 MiB
    hipMemsetAsync(out, 0, sizeof(float), stream);
    prep_comb<<<dim3((S_LEN * D / 4) / 256), dim3(256), 0, stream>>>(key, kidx, comb);
    sli_kl_fused<<<dim3(S_LEN), dim3(256), 0, stream>>>(
        query, qidx, weights, sidx, smax, ssum, comb, out);
  }
}